// Round 3
// baseline (117.971 us; speedup 1.0000x reference)
//
#include <hip/hip_runtime.h>

#define C2LOG2E 2.8853900817779268f   // 2*log2(e): exp(2x) = exp2(C2LOG2E*x)
#define LOG2E   1.4426950408889634f

__device__ __forceinline__ float sig2(float x) {   // 1/(exp2(x)+1)
    return __builtin_amdgcn_rcpf(__builtin_amdgcn_exp2f(x) + 1.0f);
}

// ---------------- Kernel 1: fused projections, pre-scaled by 2*log2(e) -----
// 128 threads/block (thread = h), 8 rows/block. x-row loads are block-uniform
// -> s_load_dwordx4 (scalar pipe); W column loads coalesced, reused across 8
// rows in registers. blocks 0..127: qc rows; 128..639: kct (tiled transpose
// kct[b][kv>>6][h][kv&63]).
__global__ __launch_bounds__(128) void proj_kernel(
    const float* __restrict__ q_in, const float* __restrict__ k_in,
    const float* __restrict__ Wq, const float* __restrict__ Wk,
    float* __restrict__ qc, float* __restrict__ kct)
{
    int h   = threadIdx.x;              // 0..127
    int blk = blockIdx.x;               // 0..639
    bool is_q = (blk < 128);
    int r0 = is_q ? blk*8 : (blk-128)*8;          // row base in its matrix
    const float* X = (is_q ? q_in : k_in) + (size_t)r0*128;
    const float* W = is_q ? Wq : Wk;

    float acc[8] = {0,0,0,0,0,0,0,0};
#pragma unroll 4
    for (int d4 = 0; d4 < 32; ++d4) {
        float w0 = W[(4*d4+0)*128 + h];
        float w1 = W[(4*d4+1)*128 + h];
        float w2 = W[(4*d4+2)*128 + h];
        float w3 = W[(4*d4+3)*128 + h];
#pragma unroll
        for (int r = 0; r < 8; ++r) {   // x loads: uniform address -> s_load
            float4 xv = *(const float4*)(X + (size_t)r*128 + 4*d4);
            acc[r] = fmaf(xv.x, w0,
                     fmaf(xv.y, w1,
                     fmaf(xv.z, w2,
                     fmaf(xv.w, w3, acc[r]))));
        }
    }
#pragma unroll
    for (int r = 0; r < 8; ++r) acc[r] *= C2LOG2E;

    if (is_q) {
#pragma unroll
        for (int r = 0; r < 8; ++r) qc[(size_t)(r0 + r)*128 + h] = acc[r];
    } else {
        int bb = r0 >> 10;              // batch
        int c  = (r0 & 1023) >> 6;      // 64-kv chunk
        int i0 = r0 & 63;               // offset in chunk (mult of 8)
        float* dst = kct + (((size_t)(bb*16 + c))*128 + h)*64 + i0;
        *(float4*)dst       = make_float4(acc[0], acc[1], acc[2], acc[3]);
        *(float4*)(dst + 4) = make_float4(acc[4], acc[5], acc[6], acc[7]);
    }
}

// ---------------- Kernel 2: fused scores + masked softmax + PV -------------
// grid (64 q-tiles, 4 b), 512 threads, Q_TILE=4. Thread: 4 q x kv {kvl,kvl+512}.
// score'(q,kv) = -2 * sum_h wv[h]/(exp2(qc+kc)+1)  (const Sum(wv) cancels in
// softmax). Wave w owns kv chunks w and w+8; fully-masked spans are skipped.
__global__ __launch_bounds__(512, 2) void attn_kernel(
    const float* __restrict__ qc, const float* __restrict__ kct,
    const float* __restrict__ values, const int* __restrict__ valid_lens,
    const float* __restrict__ wv, float* __restrict__ out)
{
    __shared__ float4 e4_s[1024];       // (e_q0..e_q3) per kv   16 KB
    __shared__ float4 po[8][4][64];     // PV wave partials      32 KB
    __shared__ float  red_m[8][4], red_s[8][4];

    int tid  = threadIdx.x;
    int b    = blockIdx.y;
    int q0   = blockIdx.x * 4;
    int w    = tid >> 6;                // wave 0..7
    int lane = tid & 63;
    int kvl  = tid & 511;               // kv lane: owns kvl and kvl+512
    int vl   = valid_lens[b];

    // q rows + wv: block-uniform addresses -> scalar loads
    const float4* q40 = (const float4*)(qc + (size_t)(b*256 + q0)*128);
    const float4* wv4 = (const float4*)wv;
    const float* p0 = kct + ((size_t)(b*16 + w))*8192 + lane;      // chunk w
    const float* p1 = kct + ((size_t)(b*16 + w + 8))*8192 + lane;  // chunk w+8

    bool act0 = (w*64 < vl);
    bool act1 = ((w + 8)*64 < vl);
    float a0[4] = {0,0,0,0}, a1[4] = {0,0,0,0};

    if (act1) {
        for (int hb = 0; hb < 32; ++hb) {
            float4 wvv = wv4[hb];
            float4 k0 = make_float4(p0[0], p0[64], p0[128], p0[192]);
            float4 k1 = make_float4(p1[0], p1[64], p1[128], p1[192]);
            p0 += 256; p1 += 256;
#pragma unroll
            for (int q = 0; q < 4; ++q) {
                float4 qv = q40[q*32 + hb];
                a0[q] = fmaf(wvv.x, sig2(qv.x + k0.x), a0[q]);
                a1[q] = fmaf(wvv.x, sig2(qv.x + k1.x), a1[q]);
                a0[q] = fmaf(wvv.y, sig2(qv.y + k0.y), a0[q]);
                a1[q] = fmaf(wvv.y, sig2(qv.y + k1.y), a1[q]);
                a0[q] = fmaf(wvv.z, sig2(qv.z + k0.z), a0[q]);
                a1[q] = fmaf(wvv.z, sig2(qv.z + k1.z), a1[q]);
                a0[q] = fmaf(wvv.w, sig2(qv.w + k0.w), a0[q]);
                a1[q] = fmaf(wvv.w, sig2(qv.w + k1.w), a1[q]);
            }
        }
    } else if (act0) {
        for (int hb = 0; hb < 32; ++hb) {
            float4 wvv = wv4[hb];
            float4 k0 = make_float4(p0[0], p0[64], p0[128], p0[192]);
            p0 += 256;
#pragma unroll
            for (int q = 0; q < 4; ++q) {
                float4 qv = q40[q*32 + hb];
                a0[q] = fmaf(wvv.x, sig2(qv.x + k0.x), a0[q]);
                a0[q] = fmaf(wvv.y, sig2(qv.y + k0.y), a0[q]);
                a0[q] = fmaf(wvv.z, sig2(qv.z + k0.z), a0[q]);
                a0[q] = fmaf(wvv.w, sig2(qv.w + k0.w), a0[q]);
            }
        }
    }

    // ---- mask + softmax ----
    bool v0 = (kvl < vl), v1 = (kvl + 512 < vl);
    float s0[4], s1[4], m[4];
#pragma unroll
    for (int q = 0; q < 4; ++q) {
        s0[q] = v0 ? -2.f*a0[q] : -1e6f;
        s1[q] = v1 ? -2.f*a1[q] : -1e6f;
        m[q]  = fmaxf(s0[q], s1[q]);
    }
#pragma unroll
    for (int off = 32; off; off >>= 1)
#pragma unroll
        for (int q = 0; q < 4; ++q) m[q] = fmaxf(m[q], __shfl_xor(m[q], off));
    if (lane == 0) {
#pragma unroll
        for (int q = 0; q < 4; ++q) red_m[w][q] = m[q];
    }
    __syncthreads();
#pragma unroll
    for (int q = 0; q < 4; ++q) {
        m[q] = red_m[0][q];
#pragma unroll
        for (int ww = 1; ww < 8; ++ww) m[q] = fmaxf(m[q], red_m[ww][q]);
    }

    float e0[4], e1[4], l[4];
#pragma unroll
    for (int q = 0; q < 4; ++q) {
        e0[q] = __builtin_amdgcn_exp2f((s0[q] - m[q]) * LOG2E);
        e1[q] = __builtin_amdgcn_exp2f((s1[q] - m[q]) * LOG2E);
        l[q]  = e0[q] + e1[q];
    }
    e4_s[kvl]       = make_float4(e0[0], e0[1], e0[2], e0[3]);
    e4_s[kvl + 512] = make_float4(e1[0], e1[1], e1[2], e1[3]);
#pragma unroll
    for (int off = 32; off; off >>= 1)
#pragma unroll
        for (int q = 0; q < 4; ++q) l[q] += __shfl_xor(l[q], off);
    if (lane == 0) {
#pragma unroll
        for (int q = 0; q < 4; ++q) red_s[w][q] = l[q];
    }
    __syncthreads();
    float inv[4];
#pragma unroll
    for (int q = 0; q < 4; ++q) {
        float s = red_s[0][q];
#pragma unroll
        for (int ww = 1; ww < 8; ++ww) s += red_s[ww][q];
        inv[q] = 1.0f / s;
    }

    // ---- PV: wave w takes kv = w, w+8, ... (< vl; e==0 beyond) ----
    int kv_end = (vl == 0) ? 1024 : vl;
    float4 ac[4] = {{0,0,0,0},{0,0,0,0},{0,0,0,0},{0,0,0,0}};
    const float4* V4 = (const float4*)values + (size_t)b*1024*64 + lane;
#pragma unroll 2
    for (int kv = w; kv < kv_end; kv += 8) {
        float4 vv = V4[(size_t)kv*64];      // coalesced 1 KB/wave
        float4 ee = e4_s[kv];               // LDS broadcast
        ac[0].x = fmaf(ee.x, vv.x, ac[0].x); ac[0].y = fmaf(ee.x, vv.y, ac[0].y);
        ac[0].z = fmaf(ee.x, vv.z, ac[0].z); ac[0].w = fmaf(ee.x, vv.w, ac[0].w);
        ac[1].x = fmaf(ee.y, vv.x, ac[1].x); ac[1].y = fmaf(ee.y, vv.y, ac[1].y);
        ac[1].z = fmaf(ee.y, vv.z, ac[1].z); ac[1].w = fmaf(ee.y, vv.w, ac[1].w);
        ac[2].x = fmaf(ee.z, vv.x, ac[2].x); ac[2].y = fmaf(ee.z, vv.y, ac[2].y);
        ac[2].z = fmaf(ee.z, vv.z, ac[2].z); ac[2].w = fmaf(ee.z, vv.w, ac[2].w);
        ac[3].x = fmaf(ee.w, vv.x, ac[3].x); ac[3].y = fmaf(ee.w, vv.y, ac[3].y);
        ac[3].z = fmaf(ee.w, vv.z, ac[3].z); ac[3].w = fmaf(ee.w, vv.w, ac[3].w);
    }
#pragma unroll
    for (int q = 0; q < 4; ++q) po[w][q][lane] = ac[q];
    __syncthreads();

    // ---- combine wave partials: thread -> (q = tid>>7, 2 v-cols) ----
    int qq  = tid >> 7;
    int col = (tid & 127) * 2;
    const float* pp = (const float*)po;     // [(w*4+q)*256 + col]
    float rx = 0.f, ry = 0.f;
#pragma unroll
    for (int ww = 0; ww < 8; ++ww) {
        float2 p = *(const float2*)&pp[(ww*4 + qq)*256 + col];
        rx += p.x; ry += p.y;
    }
    float iv = inv[qq];
    *(float2*)&out[((size_t)(b*256 + q0 + qq))*256 + col] =
        make_float2(rx * iv, ry * iv);
}

extern "C" void kernel_launch(void* const* d_in, const int* in_sizes, int n_in,
                              void* d_out, int out_size, void* d_ws, size_t ws_size,
                              hipStream_t stream)
{
    const float* queries = (const float*)d_in[0];   // [4,256,128]
    const float* keys    = (const float*)d_in[1];   // [4,1024,128]
    const float* values  = (const float*)d_in[2];   // [4,1024,256]
    const int*   vlens   = (const int*)d_in[3];     // [4]
    const float* Wq      = (const float*)d_in[4];   // [128,128]
    const float* Wk      = (const float*)d_in[5];   // [128,128]
    const float* wv      = (const float*)d_in[6];   // [128]
    float* out = (float*)d_out;                     // [4,256,256]

    float* qc  = (float*)d_ws;                      // 4*256*128 floats
    float* kct = qc + 4*256*128;                    // 4*16*128*64 floats

    proj_kernel<<<640, 128, 0, stream>>>(queries, keys, Wq, Wk, qc, kct);
    attn_kernel<<<dim3(64, 4), 512, 0, stream>>>(qc, kct, values, vlens, wv, out);
}

// Round 4
// 106.260 us; speedup vs baseline: 1.1102x; 1.1102x over previous
//
#include <hip/hip_runtime.h>

#define C2LOG2E 2.8853900817779268f   // 2*log2(e): exp(2x) = exp2(C2LOG2E*x)
#define LOG2E   1.4426950408889634f

__device__ __forceinline__ float sig2(float x) {   // 1/(exp2(x)+1)
    return __builtin_amdgcn_rcpf(__builtin_amdgcn_exp2f(x) + 1.0f);
}

// ---------------- Kernel 1: fused projections, pre-scaled by 2*log2(e) -----
// 256 threads, 8 rows/block, grid 640. x rows staged in LDS, read as
// wave-uniform ds_read_b128 broadcast; W columns coalesced, reused x8 rows.
// Thread = (h, d-half); halves combined through LDS.
// blocks 0..127: qc rows; 128..639: kct tiled transpose kct[b][kv>>6][h][kv&63].
__global__ __launch_bounds__(256) void proj_kernel(
    const float* __restrict__ q_in, const float* __restrict__ k_in,
    const float* __restrict__ Wq, const float* __restrict__ Wk,
    float* __restrict__ qc, float* __restrict__ kct)
{
    __shared__ __align__(16) float x_s[8][128];   // 4 KB
    __shared__ float ps[2][8][128];               // 8 KB
    int tid = threadIdx.x;
    int blk = blockIdx.x;
    bool is_q = (blk < 128);
    int r0 = (is_q ? blk : blk - 128) * 8;
    const float* X = (is_q ? q_in : k_in) + (size_t)r0 * 128;
    const float* W = is_q ? Wq : Wk;

    {   // stage 8 rows, coalesced float4
        float4 v = ((const float4*)X)[tid];
        *(float4*)&x_s[tid >> 5][(tid & 31) * 4] = v;
    }
    __syncthreads();

    int h    = tid & 127;
    int half = tid >> 7;
    int d0   = half * 64;
    float acc[8] = {0,0,0,0,0,0,0,0};
#pragma unroll 2
    for (int i4 = 0; i4 < 16; ++i4) {
        int d = d0 + 4*i4;
        float w0 = W[(d+0)*128 + h];          // coalesced, reused x8
        float w1 = W[(d+1)*128 + h];
        float w2 = W[(d+2)*128 + h];
        float w3 = W[(d+3)*128 + h];
#pragma unroll
        for (int r = 0; r < 8; ++r) {
            float4 xv = *(const float4*)&x_s[r][d];   // wave-uniform broadcast
            acc[r] = fmaf(xv.x, w0, fmaf(xv.y, w1,
                     fmaf(xv.z, w2, fmaf(xv.w, w3, acc[r]))));
        }
    }
#pragma unroll
    for (int r = 0; r < 8; ++r) ps[half][r][h] = acc[r];
    __syncthreads();

    // combine halves: thread covers rows rq*4..rq*4+3, column h
    int rq = tid >> 7;
    float v0 = (ps[0][rq*4+0][h] + ps[1][rq*4+0][h]) * C2LOG2E;
    float v1 = (ps[0][rq*4+1][h] + ps[1][rq*4+1][h]) * C2LOG2E;
    float v2 = (ps[0][rq*4+2][h] + ps[1][rq*4+2][h]) * C2LOG2E;
    float v3 = (ps[0][rq*4+3][h] + ps[1][rq*4+3][h]) * C2LOG2E;

    if (is_q) {
        qc[(size_t)(r0 + rq*4 + 0)*128 + h] = v0;
        qc[(size_t)(r0 + rq*4 + 1)*128 + h] = v1;
        qc[(size_t)(r0 + rq*4 + 2)*128 + h] = v2;
        qc[(size_t)(r0 + rq*4 + 3)*128 + h] = v3;
    } else {
        int bb = r0 >> 10;              // batch
        int c  = (r0 & 1023) >> 6;      // 64-kv chunk
        int i0 = (r0 & 63) + rq*4;      // offset in chunk
        float* dst = kct + (((size_t)(bb*16 + c))*128 + h)*64 + i0;
        *(float4*)dst = make_float4(v0, v1, v2, v3);   // contiguous along kv
    }
}

// ---------------- Kernel 2: fused scores + masked softmax + PV -------------
// grid (64 q-tiles, 4 b) = 256 blocks, 1024 threads (16 waves -> 16 waves/CU).
// Thread owns 1 kv, 4 queries. score'(q,kv) = -2*sum_h wv[h]/(exp2(qc+kc)+1)
// (constant Sum(wv) cancels in softmax). Wave w owns kv chunk w; fully-masked
// chunks skip the h-loop. PV partials folded 16->8 waves, then tree-combined.
__global__ __launch_bounds__(1024, 4) void attn_kernel(
    const float* __restrict__ qc, const float* __restrict__ kct,
    const float* __restrict__ values, const int* __restrict__ valid_lens,
    const float* __restrict__ wv, float* __restrict__ out)
{
    __shared__ float4 e4_s[1024];       // (e_q0..e_q3) per kv     16 KB
    __shared__ float4 po8[8][4][64];    // folded PV partials      32 KB
    __shared__ float4 red_m[16], red_s[16];

    int tid  = threadIdx.x;
    int b    = blockIdx.y;
    int q0   = blockIdx.x * 4;
    int w    = tid >> 6;                // wave 0..15
    int lane = tid & 63;
    int kv   = tid;                     // 0..1023
    int vl   = valid_lens[b];

    const float4* q40 = (const float4*)(qc + (size_t)(b*256 + q0)*128);
    const float4* wv4 = (const float4*)wv;
    const float* p = kct + ((size_t)(b*16 + w))*8192 + lane;   // chunk w

    float a[4] = {0,0,0,0};
    if (w*64 < vl) {                    // wave-uniform skip of masked chunks
        for (int hb = 0; hb < 32; ++hb) {
            float4 wvv = wv4[hb];
            float4 k = make_float4(p[0], p[64], p[128], p[192]);
            p += 256;
#pragma unroll
            for (int q = 0; q < 4; ++q) {
                float4 qv = q40[q*32 + hb];
                a[q] = fmaf(wvv.x, sig2(qv.x + k.x), a[q]);
                a[q] = fmaf(wvv.y, sig2(qv.y + k.y), a[q]);
                a[q] = fmaf(wvv.z, sig2(qv.z + k.z), a[q]);
                a[q] = fmaf(wvv.w, sig2(qv.w + k.w), a[q]);
            }
        }
    }

    // ---- mask + softmax ----
    bool valid = (kv < vl);
    float s[4], m[4];
#pragma unroll
    for (int q = 0; q < 4; ++q) {
        s[q] = valid ? -2.f*a[q] : -1e6f;
        m[q] = s[q];
    }
#pragma unroll
    for (int off = 32; off; off >>= 1)
#pragma unroll
        for (int q = 0; q < 4; ++q) m[q] = fmaxf(m[q], __shfl_xor(m[q], off));
    if (lane == 0) red_m[w] = make_float4(m[0], m[1], m[2], m[3]);
    __syncthreads();
    {
        float4 mm = red_m[0];
#pragma unroll
        for (int ww = 1; ww < 16; ++ww) {
            float4 t = red_m[ww];
            mm.x = fmaxf(mm.x, t.x); mm.y = fmaxf(mm.y, t.y);
            mm.z = fmaxf(mm.z, t.z); mm.w = fmaxf(mm.w, t.w);
        }
        m[0] = mm.x; m[1] = mm.y; m[2] = mm.z; m[3] = mm.w;
    }

    float e[4], l[4];
#pragma unroll
    for (int q = 0; q < 4; ++q) {
        e[q] = __builtin_amdgcn_exp2f((s[q] - m[q]) * LOG2E);
        l[q] = e[q];
    }
    e4_s[kv] = make_float4(e[0], e[1], e[2], e[3]);
#pragma unroll
    for (int off = 32; off; off >>= 1)
#pragma unroll
        for (int q = 0; q < 4; ++q) l[q] += __shfl_xor(l[q], off);
    if (lane == 0) red_s[w] = make_float4(l[0], l[1], l[2], l[3]);
    __syncthreads();
    float inv[4];
    {
        float4 ss = red_s[0];
#pragma unroll
        for (int ww = 1; ww < 16; ++ww) {
            float4 t = red_s[ww];
            ss.x += t.x; ss.y += t.y; ss.z += t.z; ss.w += t.w;
        }
        inv[0] = 1.0f/ss.x; inv[1] = 1.0f/ss.y; inv[2] = 1.0f/ss.z; inv[3] = 1.0f/ss.w;
    }

    // ---- PV: wave w takes kv = w, w+16, ... (< vl; e==0 beyond) ----
    int kv_end = (vl == 0) ? 1024 : vl;
    float4 ac[4] = {{0,0,0,0},{0,0,0,0},{0,0,0,0},{0,0,0,0}};
    const float4* V4 = (const float4*)values + (size_t)b*65536 + lane;
#pragma unroll 2
    for (int k2 = w; k2 < kv_end; k2 += 16) {
        float4 vv = V4[(size_t)k2*64];      // coalesced 1 KB/wave
        float4 ee = e4_s[k2];               // LDS broadcast
        ac[0].x = fmaf(ee.x, vv.x, ac[0].x); ac[0].y = fmaf(ee.x, vv.y, ac[0].y);
        ac[0].z = fmaf(ee.x, vv.z, ac[0].z); ac[0].w = fmaf(ee.x, vv.w, ac[0].w);
        ac[1].x = fmaf(ee.y, vv.x, ac[1].x); ac[1].y = fmaf(ee.y, vv.y, ac[1].y);
        ac[1].z = fmaf(ee.y, vv.z, ac[1].z); ac[1].w = fmaf(ee.y, vv.w, ac[1].w);
        ac[2].x = fmaf(ee.z, vv.x, ac[2].x); ac[2].y = fmaf(ee.z, vv.y, ac[2].y);
        ac[2].z = fmaf(ee.z, vv.z, ac[2].z); ac[2].w = fmaf(ee.z, vv.w, ac[2].w);
        ac[3].x = fmaf(ee.w, vv.x, ac[3].x); ac[3].y = fmaf(ee.w, vv.y, ac[3].y);
        ac[3].z = fmaf(ee.w, vv.z, ac[3].z); ac[3].w = fmaf(ee.w, vv.w, ac[3].w);
    }

    // fold 16 wave-partials -> 8 slots, then tree-combine
    if (w >= 8) {
#pragma unroll
        for (int q = 0; q < 4; ++q) po8[w-8][q][lane] = ac[q];
    }
    __syncthreads();
    if (w < 8) {
#pragma unroll
        for (int q = 0; q < 4; ++q) {
            float4 t = po8[w][q][lane];
            t.x += ac[q].x; t.y += ac[q].y; t.z += ac[q].z; t.w += ac[q].w;
            po8[w][q][lane] = t;            // same thread's slot: no race
        }
    }
    __syncthreads();

    // ---- combine 8 slots: thread -> one output element ----
    int qq  = tid >> 8;                 // 0..3
    int col = tid & 255;
    const float* pp = (const float*)po8;    // [(w*4+q)*256 + col]
    float r = 0.f;
#pragma unroll
    for (int ww = 0; ww < 8; ++ww) r += pp[(ww*4 + qq)*256 + col];
    out[((size_t)(b*256 + q0 + qq))*256 + col] = r * inv[qq];
}

extern "C" void kernel_launch(void* const* d_in, const int* in_sizes, int n_in,
                              void* d_out, int out_size, void* d_ws, size_t ws_size,
                              hipStream_t stream)
{
    const float* queries = (const float*)d_in[0];   // [4,256,128]
    const float* keys    = (const float*)d_in[1];   // [4,1024,128]
    const float* values  = (const float*)d_in[2];   // [4,1024,256]
    const int*   vlens   = (const int*)d_in[3];     // [4]
    const float* Wq      = (const float*)d_in[4];   // [128,128]
    const float* Wk      = (const float*)d_in[5];   // [128,128]
    const float* wv      = (const float*)d_in[6];   // [128]
    float* out = (float*)d_out;                     // [4,256,256]

    float* qc  = (float*)d_ws;                      // 4*256*128 floats
    float* kct = qc + 4*256*128;                    // 4*16*128*64 floats

    proj_kernel<<<640, 256, 0, stream>>>(queries, keys, Wq, Wk, qc, kct);
    attn_kernel<<<dim3(64, 4), 1024, 0, stream>>>(qc, kct, values, vlens, wv, out);
}

// Round 5
// 103.232 us; speedup vs baseline: 1.1428x; 1.0293x over previous
//
#include <hip/hip_runtime.h>

#define C2LOG2E 2.8853900817779268f   // 2*log2(e): exp(2x) = exp2(C2LOG2E*x)
#define LOG2E   1.4426950408889634f

__device__ __forceinline__ float sig2(float x) {   // 1/(exp2(x)+1)
    return __builtin_amdgcn_rcpf(__builtin_amdgcn_exp2f(x) + 1.0f);
}

// ---------------- Kernel 1: fused projections, pre-scaled by 2*log2(e) -----
// 256 threads, 8 rows/block, grid 640. x rows staged in LDS (wave-uniform
// ds_read_b128 broadcast); W columns coalesced, reused x8 rows.
// blocks 0..127: qc rows. blocks 128..639: kct4 layout [b][c][h>>2][kv][h&3]
// so attn reads one dwordx4 (4 h-values) per lane per iteration.
__global__ __launch_bounds__(256) void proj_kernel(
    const float* __restrict__ q_in, const float* __restrict__ k_in,
    const float* __restrict__ Wq, const float* __restrict__ Wk,
    float* __restrict__ qc, float* __restrict__ kct)
{
    __shared__ __align__(16) float x_s[8][128];   // 4 KB
    __shared__ float ps[2][8][128];               // 8 KB
    int tid = threadIdx.x;
    int blk = blockIdx.x;
    bool is_q = (blk < 128);
    int r0 = (is_q ? blk : blk - 128) * 8;
    const float* X = (is_q ? q_in : k_in) + (size_t)r0 * 128;
    const float* W = is_q ? Wq : Wk;

    {   // stage 8 rows, coalesced float4
        float4 v = ((const float4*)X)[tid];
        *(float4*)&x_s[tid >> 5][(tid & 31) * 4] = v;
    }
    __syncthreads();

    int h    = tid & 127;
    int half = tid >> 7;
    int d0   = half * 64;
    float acc[8] = {0,0,0,0,0,0,0,0};
#pragma unroll 2
    for (int i4 = 0; i4 < 16; ++i4) {
        int d = d0 + 4*i4;
        float w0 = W[(d+0)*128 + h];          // coalesced, reused x8
        float w1 = W[(d+1)*128 + h];
        float w2 = W[(d+2)*128 + h];
        float w3 = W[(d+3)*128 + h];
#pragma unroll
        for (int r = 0; r < 8; ++r) {
            float4 xv = *(const float4*)&x_s[r][d];   // wave-uniform broadcast
            acc[r] = fmaf(xv.x, w0, fmaf(xv.y, w1,
                     fmaf(xv.z, w2, fmaf(xv.w, w3, acc[r]))));
        }
    }
#pragma unroll
    for (int r = 0; r < 8; ++r) ps[half][r][h] = acc[r];
    __syncthreads();

    // combine halves: thread covers rows rq*4..rq*4+3, column h
    int rq = tid >> 7;
    float v0 = (ps[0][rq*4+0][h] + ps[1][rq*4+0][h]) * C2LOG2E;
    float v1 = (ps[0][rq*4+1][h] + ps[1][rq*4+1][h]) * C2LOG2E;
    float v2 = (ps[0][rq*4+2][h] + ps[1][rq*4+2][h]) * C2LOG2E;
    float v3 = (ps[0][rq*4+3][h] + ps[1][rq*4+3][h]) * C2LOG2E;

    if (is_q) {
        qc[(size_t)(r0 + rq*4 + 0)*128 + h] = v0;
        qc[(size_t)(r0 + rq*4 + 1)*128 + h] = v1;
        qc[(size_t)(r0 + rq*4 + 2)*128 + h] = v2;
        qc[(size_t)(r0 + rq*4 + 3)*128 + h] = v3;
    } else {
        int bb = r0 >> 10;              // batch
        int c  = (r0 & 1023) >> 6;      // 64-kv chunk
        int i0 = (r0 & 63) + rq*4;      // this thread's 4 kv in chunk
        // kct4 element: (((b*16+c)*32 + (h>>2))*64 + kv)*4 + (h&3)
        float* dst = kct + ((((size_t)(bb*16 + c))*32 + (h >> 2))*64 + i0)*4 + (h & 3);
        dst[0]  = v0;
        dst[4]  = v1;
        dst[8]  = v2;
        dst[12] = v3;
    }
}

// ---------------- Kernel 2: fused scores + masked softmax + PV -------------
// grid (64 q-tiles, 4 b) = 256 blocks, 1024 threads, Q_TILE=4.
// Mask-balanced mapping: wave w -> (chunks {w&7, (w&7)+8}, queries qh=w>>3
// covering {2qh, 2qh+1}). With vl<=512 every wave has 1 active chunk x 2 q
// (perfect balance); score'(q,kv) = -2*sum_h wv[h]/(exp2(qc+kc)+1) (constant
// Sum(wv) cancels in softmax). PV: wave w owns kv stripe w step 16, all 4 q.
__global__ __launch_bounds__(1024, 4) void attn_kernel(
    const float* __restrict__ qc, const float* __restrict__ kct,
    const float* __restrict__ values, const int* __restrict__ valid_lens,
    const float* __restrict__ wv, float* __restrict__ out)
{
    __shared__ float2 e2_s[2][1024];    // [qh][kv] = (e_{2qh}, e_{2qh+1}) 16 KB
    __shared__ float4 po8[8][4][64];    // folded PV partials              32 KB
    __shared__ float2 red_m[16], red_s[16];

    int tid  = threadIdx.x;
    int b    = blockIdx.y;
    int q0   = blockIdx.x * 4;
    int w    = tid >> 6;                // wave 0..15
    int lane = tid & 63;
    int qh   = w >> 3;                  // query pair {2qh, 2qh+1}
    int c0   = w & 7;                   // chunks c0 and c0+8
    int vl   = valid_lens[b];

    // q rows (2) + wv: block/wave-uniform addresses -> scalar loads
    const float4* qa4 = (const float4*)(qc + (size_t)(b*256 + q0 + 2*qh)*128);
    const float4* qb4 = qa4 + 32;
    const float4* wv4 = (const float4*)wv;
    const float4* kb  = (const float4*)kct;     // [b][c][hg][kv] float4 units
    const float4* p0  = kb + ((size_t)(b*16 + c0))*2048 + lane;
    const float4* p1  = p0 + 8*2048;

    bool act0 = (c0*64 < vl);
    bool act1 = ((c0 + 8)*64 < vl);
    float a00=0.f, a10=0.f, a01=0.f, a11=0.f;   // a[q-in-pair][chunk]

    if (act1) {                         // both chunks active
        for (int hb = 0; hb < 32; ++hb) {
            float4 wvv = wv4[hb];
            float4 qa = qa4[hb], qb = qb4[hb];
            float4 k0 = p0[(size_t)hb*64];       // one dwordx4: h..h+3 of kv
            float4 k1 = p1[(size_t)hb*64];
            a00 = fmaf(wvv.x, sig2(qa.x + k0.x), a00);
            a10 = fmaf(wvv.x, sig2(qb.x + k0.x), a10);
            a01 = fmaf(wvv.x, sig2(qa.x + k1.x), a01);
            a11 = fmaf(wvv.x, sig2(qb.x + k1.x), a11);
            a00 = fmaf(wvv.y, sig2(qa.y + k0.y), a00);
            a10 = fmaf(wvv.y, sig2(qb.y + k0.y), a10);
            a01 = fmaf(wvv.y, sig2(qa.y + k1.y), a01);
            a11 = fmaf(wvv.y, sig2(qb.y + k1.y), a11);
            a00 = fmaf(wvv.z, sig2(qa.z + k0.z), a00);
            a10 = fmaf(wvv.z, sig2(qb.z + k0.z), a10);
            a01 = fmaf(wvv.z, sig2(qa.z + k1.z), a01);
            a11 = fmaf(wvv.z, sig2(qb.z + k1.z), a11);
            a00 = fmaf(wvv.w, sig2(qa.w + k0.w), a00);
            a10 = fmaf(wvv.w, sig2(qb.w + k0.w), a10);
            a01 = fmaf(wvv.w, sig2(qa.w + k1.w), a01);
            a11 = fmaf(wvv.w, sig2(qb.w + k1.w), a11);
        }
    } else if (act0) {                  // only low chunk active
        for (int hb = 0; hb < 32; ++hb) {
            float4 wvv = wv4[hb];
            float4 qa = qa4[hb], qb = qb4[hb];
            float4 k0 = p0[(size_t)hb*64];
            a00 = fmaf(wvv.x, sig2(qa.x + k0.x), a00);
            a10 = fmaf(wvv.x, sig2(qb.x + k0.x), a10);
            a00 = fmaf(wvv.y, sig2(qa.y + k0.y), a00);
            a10 = fmaf(wvv.y, sig2(qb.y + k0.y), a10);
            a00 = fmaf(wvv.z, sig2(qa.z + k0.z), a00);
            a10 = fmaf(wvv.z, sig2(qb.z + k0.z), a10);
            a00 = fmaf(wvv.w, sig2(qa.w + k0.w), a00);
            a10 = fmaf(wvv.w, sig2(qb.w + k0.w), a10);
        }
    }

    // ---- mask + softmax (this wave: 2 queries x kv {kv0, kv1}) ----
    int kv0 = c0*64 + lane, kv1 = kv0 + 512;
    bool m0v = (kv0 < vl), m1v = (kv1 < vl);
    float s00 = m0v ? -2.f*a00 : -1e6f;
    float s10 = m0v ? -2.f*a10 : -1e6f;
    float s01 = m1v ? -2.f*a01 : -1e6f;
    float s11 = m1v ? -2.f*a11 : -1e6f;

    float m0 = fmaxf(s00, s01), m1 = fmaxf(s10, s11);
#pragma unroll
    for (int off = 32; off; off >>= 1) {
        m0 = fmaxf(m0, __shfl_xor(m0, off));
        m1 = fmaxf(m1, __shfl_xor(m1, off));
    }
    if (lane == 0) red_m[w] = make_float2(m0, m1);
    __syncthreads();
    {
        float2 mm = red_m[qh*8];
#pragma unroll
        for (int ww = 1; ww < 8; ++ww) {
            float2 t = red_m[qh*8 + ww];
            mm.x = fmaxf(mm.x, t.x); mm.y = fmaxf(mm.y, t.y);
        }
        m0 = mm.x; m1 = mm.y;
    }

    float e00 = __builtin_amdgcn_exp2f((s00 - m0) * LOG2E);
    float e10 = __builtin_amdgcn_exp2f((s10 - m1) * LOG2E);
    float e01 = __builtin_amdgcn_exp2f((s01 - m0) * LOG2E);
    float e11 = __builtin_amdgcn_exp2f((s11 - m1) * LOG2E);
    e2_s[qh][kv0] = make_float2(e00, e10);
    e2_s[qh][kv1] = make_float2(e01, e11);
    float l0 = e00 + e01, l1 = e10 + e11;
#pragma unroll
    for (int off = 32; off; off >>= 1) {
        l0 += __shfl_xor(l0, off);
        l1 += __shfl_xor(l1, off);
    }
    if (lane == 0) red_s[w] = make_float2(l0, l1);
    __syncthreads();

    // ---- PV: wave w takes kv = w, w+16, ... (< vl; e==0 beyond) ----
    int kv_end = (vl == 0) ? 1024 : vl;
    float4 ac[4] = {{0,0,0,0},{0,0,0,0},{0,0,0,0},{0,0,0,0}};
    const float4* V4 = (const float4*)values + (size_t)b*65536 + lane;
#pragma unroll 2
    for (int k2 = w; k2 < kv_end; k2 += 16) {
        float4 vv = V4[(size_t)k2*64];      // coalesced 1 KB/wave
        float2 ea = e2_s[0][k2];            // (e_q0, e_q1) broadcast
        float2 eb = e2_s[1][k2];            // (e_q2, e_q3)
        ac[0].x = fmaf(ea.x, vv.x, ac[0].x); ac[0].y = fmaf(ea.x, vv.y, ac[0].y);
        ac[0].z = fmaf(ea.x, vv.z, ac[0].z); ac[0].w = fmaf(ea.x, vv.w, ac[0].w);
        ac[1].x = fmaf(ea.y, vv.x, ac[1].x); ac[1].y = fmaf(ea.y, vv.y, ac[1].y);
        ac[1].z = fmaf(ea.y, vv.z, ac[1].z); ac[1].w = fmaf(ea.y, vv.w, ac[1].w);
        ac[2].x = fmaf(eb.x, vv.x, ac[2].x); ac[2].y = fmaf(eb.x, vv.y, ac[2].y);
        ac[2].z = fmaf(eb.x, vv.z, ac[2].z); ac[2].w = fmaf(eb.x, vv.w, ac[2].w);
        ac[3].x = fmaf(eb.y, vv.x, ac[3].x); ac[3].y = fmaf(eb.y, vv.y, ac[3].y);
        ac[3].z = fmaf(eb.y, vv.z, ac[3].z); ac[3].w = fmaf(eb.y, vv.w, ac[3].w);
    }

    // fold 16 wave-partials -> 8 slots, then tree-combine
    if (w >= 8) {
#pragma unroll
        for (int q = 0; q < 4; ++q) po8[w-8][q][lane] = ac[q];
    }
    __syncthreads();
    if (w < 8) {
#pragma unroll
        for (int q = 0; q < 4; ++q) {
            float4 t = po8[w][q][lane];
            t.x += ac[q].x; t.y += ac[q].y; t.z += ac[q].z; t.w += ac[q].w;
            po8[w][q][lane] = t;            // own slot: no race
        }
    }
    __syncthreads();

    // ---- combine 8 slots; normalize with sum rebuilt from red_s ----
    int qq  = tid >> 8;                 // 0..3
    int col = tid & 255;
    float ssum = 0.f;
#pragma unroll
    for (int ww = 0; ww < 8; ++ww) {
        float2 t = red_s[(qq >> 1)*8 + ww];
        ssum += (qq & 1) ? t.y : t.x;
    }
    const float* pp = (const float*)po8;    // [(w*4+q)*256 + col]
    float r = 0.f;
#pragma unroll
    for (int ww = 0; ww < 8; ++ww) r += pp[(ww*4 + qq)*256 + col];
    out[((size_t)(b*256 + q0 + qq))*256 + col] = r / ssum;
}

extern "C" void kernel_launch(void* const* d_in, const int* in_sizes, int n_in,
                              void* d_out, int out_size, void* d_ws, size_t ws_size,
                              hipStream_t stream)
{
    const float* queries = (const float*)d_in[0];   // [4,256,128]
    const float* keys    = (const float*)d_in[1];   // [4,1024,128]
    const float* values  = (const float*)d_in[2];   // [4,1024,256]
    const int*   vlens   = (const int*)d_in[3];     // [4]
    const float* Wq      = (const float*)d_in[4];   // [128,128]
    const float* Wk      = (const float*)d_in[5];   // [128,128]
    const float* wv      = (const float*)d_in[6];   // [128]
    float* out = (float*)d_out;                     // [4,256,256]

    float* qc  = (float*)d_ws;                      // 4*256*128 floats
    float* kct = qc + 4*256*128;                    // 4*16*32*64*4 floats

    proj_kernel<<<640, 256, 0, stream>>>(queries, keys, Wq, Wk, qc, kct);
    attn_kernel<<<dim3(64, 4), 1024, 0, stream>>>(qc, kct, values, vlens, wv, out);
}

// Round 6
// 99.618 us; speedup vs baseline: 1.1842x; 1.0363x over previous
//
#include <hip/hip_runtime.h>

#define C2LOG2E 2.8853900817779268f   // 2*log2(e): exp(2x) = exp2(C2LOG2E*x)
#define LOG2E   1.4426950408889634f

__device__ __forceinline__ float sig2(float x) {   // 1/(exp2(x)+1)
    return __builtin_amdgcn_rcpf(__builtin_amdgcn_exp2f(x) + 1.0f);
}

// ---------------- Kernel 1: fused projections, pre-scaled by 2*log2(e) -----
// 256 threads, 8 rows/block. Thread = (hl = tid&63 -> columns {hl, hl+64},
// d-quarter = tid>>6): halves LDS b128 reads per FMA vs 1-column mapping.
// K-blocks with all rows >= valid_len exit early (attn reads those rows only
// as benign poison in partially-masked chunks; scores there are masked).
// blocks 0..127: qc rows. blocks 128..639: kct4 layout [b][c][h>>2][kv][h&3].
__global__ __launch_bounds__(256) void proj_kernel(
    const float* __restrict__ q_in, const float* __restrict__ k_in,
    const float* __restrict__ Wq, const float* __restrict__ Wk,
    const int* __restrict__ valid_lens,
    float* __restrict__ qc, float* __restrict__ kct)
{
    __shared__ __align__(16) float x_s[8][128];     // 4 KB
    __shared__ __align__(16) float ps[4][8][128];   // 16 KB
    int tid = threadIdx.x;
    int blk = blockIdx.x;
    bool is_q = (blk < 128);
    int r0 = (is_q ? blk : blk - 128) * 8;
    int bb = r0 >> 10;
    if (!is_q) {
        int vl = valid_lens[bb];
        if ((r0 & 1023) >= vl) return;  // block-uniform: whole block exits
    }
    const float* X = (is_q ? q_in : k_in) + (size_t)r0 * 128;
    const float* W = is_q ? Wq : Wk;

    *(float4*)&x_s[tid >> 5][(tid & 31) * 4] = ((const float4*)X)[tid];
    __syncthreads();

    int hl = tid & 63;                  // column pair {hl, hl+64}
    int dq = tid >> 6;                  // d-quarter (wave-uniform)
    float a0[8] = {0,0,0,0,0,0,0,0};
    float a1[8] = {0,0,0,0,0,0,0,0};
#pragma unroll
    for (int i4 = 0; i4 < 8; ++i4) {
        int d = dq*32 + i4*4;
        float w00 = W[(d+0)*128 + hl], w01 = W[(d+0)*128 + hl + 64];
        float w10 = W[(d+1)*128 + hl], w11 = W[(d+1)*128 + hl + 64];
        float w20 = W[(d+2)*128 + hl], w21 = W[(d+2)*128 + hl + 64];
        float w30 = W[(d+3)*128 + hl], w31 = W[(d+3)*128 + hl + 64];
#pragma unroll
        for (int r = 0; r < 8; ++r) {
            float4 xv = *(const float4*)&x_s[r][d];   // wave-uniform broadcast
            a0[r] = fmaf(xv.x,w00, fmaf(xv.y,w10, fmaf(xv.z,w20, fmaf(xv.w,w30, a0[r]))));
            a1[r] = fmaf(xv.x,w01, fmaf(xv.y,w11, fmaf(xv.z,w21, fmaf(xv.w,w31, a1[r]))));
        }
    }
#pragma unroll
    for (int r = 0; r < 8; ++r) {
        ps[dq][r][hl]      = a0[r];
        ps[dq][r][hl + 64] = a1[r];
    }
    __syncthreads();

    // combine 4 quarters: thread -> (row r, 4 h columns), b128 LDS reads
    int r  = tid >> 5;
    int c4 = (tid & 31) * 4;
    float4 s0 = *(const float4*)&ps[0][r][c4];
    float4 s1 = *(const float4*)&ps[1][r][c4];
    float4 s2 = *(const float4*)&ps[2][r][c4];
    float4 s3 = *(const float4*)&ps[3][r][c4];
    float4 v = make_float4(((s0.x+s1.x)+(s2.x+s3.x))*C2LOG2E,
                           ((s0.y+s1.y)+(s2.y+s3.y))*C2LOG2E,
                           ((s0.z+s1.z)+(s2.z+s3.z))*C2LOG2E,
                           ((s0.w+s1.w)+(s2.w+s3.w))*C2LOG2E);
    if (is_q) {
        *(float4*)&qc[(size_t)(r0 + r)*128 + c4] = v;
    } else {
        int c    = (r0 & 1023) >> 6;    // 64-kv chunk
        int kvin = (r0 & 63) + r;       // kv within chunk
        // kct4: (((b*16+c)*32 + h/4)*64 + kv)*4 + h%4 ; c4 % 4 == 0
        *(float4*)&kct[((((size_t)(bb*16 + c))*32 + (c4 >> 2))*64 + kvin)*4] = v;
    }
}

// ---------------- Kernel 2: fused scores + masked softmax + PV -------------
// grid (128 q-tiles, 4 b) = 512 blocks, 512 threads, Q_TILE=2 -> 2 blocks/CU:
// one block's trans-bound score phase overlaps the other's L2-bound PV phase.
// Wave w (0..7) owns kv chunks {w, w+8} (mask-balanced: for vl<=512 every
// wave has exactly 1 active chunk). score'(q,kv) = -2*sum_h wv/(exp2(qc+kc)+1)
// (constant Sum(wv) cancels in softmax). kct4 gives one dwordx4 per k-access.
__global__ __launch_bounds__(512, 4) void attn_kernel(
    const float* __restrict__ qc, const float* __restrict__ kct,
    const float* __restrict__ values, const int* __restrict__ valid_lens,
    const float* __restrict__ wv, float* __restrict__ out)
{
    __shared__ float2 e2_s[1024];       // (e_q0, e_q1) per kv   8 KB
    __shared__ float4 po[8][2][64];     // PV wave partials     16 KB
    __shared__ float2 red_m[8], red_s[8];

    int tid  = threadIdx.x;
    int b    = blockIdx.y;
    int q0   = blockIdx.x * 2;
    int w    = tid >> 6;                // wave 0..7
    int lane = tid & 63;
    int vl   = valid_lens[b];

    // q rows (2) + wv: block-uniform addresses -> scalar loads
    const float4* qa4 = (const float4*)(qc + (size_t)(b*256 + q0)*128);
    const float4* qb4 = qa4 + 32;
    const float4* wv4 = (const float4*)wv;
    const float4* kb  = (const float4*)kct;     // [b][c][hg][kv] float4 units
    const float4* p0  = kb + ((size_t)(b*16 + w))*2048 + lane;
    const float4* p1  = p0 + 8*2048;

    bool act0 = (w*64 < vl);
    bool act1 = ((w + 8)*64 < vl);
    float a00=0.f, a10=0.f, a01=0.f, a11=0.f;   // a[q][chunk]

    if (act1) {                         // both chunks active
        for (int hb = 0; hb < 32; ++hb) {
            float4 wvv = wv4[hb];
            float4 qa = qa4[hb], qb = qb4[hb];
            float4 k0 = p0[(size_t)hb*64];       // one dwordx4: 4 h of this kv
            float4 k1 = p1[(size_t)hb*64];
            a00 = fmaf(wvv.x, sig2(qa.x + k0.x), a00);
            a10 = fmaf(wvv.x, sig2(qb.x + k0.x), a10);
            a01 = fmaf(wvv.x, sig2(qa.x + k1.x), a01);
            a11 = fmaf(wvv.x, sig2(qb.x + k1.x), a11);
            a00 = fmaf(wvv.y, sig2(qa.y + k0.y), a00);
            a10 = fmaf(wvv.y, sig2(qb.y + k0.y), a10);
            a01 = fmaf(wvv.y, sig2(qa.y + k1.y), a01);
            a11 = fmaf(wvv.y, sig2(qb.y + k1.y), a11);
            a00 = fmaf(wvv.z, sig2(qa.z + k0.z), a00);
            a10 = fmaf(wvv.z, sig2(qb.z + k0.z), a10);
            a01 = fmaf(wvv.z, sig2(qa.z + k1.z), a01);
            a11 = fmaf(wvv.z, sig2(qb.z + k1.z), a11);
            a00 = fmaf(wvv.w, sig2(qa.w + k0.w), a00);
            a10 = fmaf(wvv.w, sig2(qb.w + k0.w), a10);
            a01 = fmaf(wvv.w, sig2(qa.w + k1.w), a01);
            a11 = fmaf(wvv.w, sig2(qb.w + k1.w), a11);
        }
    } else if (act0) {                  // only low chunk active
        for (int hb = 0; hb < 32; ++hb) {
            float4 wvv = wv4[hb];
            float4 qa = qa4[hb], qb = qb4[hb];
            float4 k0 = p0[(size_t)hb*64];
            a00 = fmaf(wvv.x, sig2(qa.x + k0.x), a00);
            a10 = fmaf(wvv.x, sig2(qb.x + k0.x), a10);
            a00 = fmaf(wvv.y, sig2(qa.y + k0.y), a00);
            a10 = fmaf(wvv.y, sig2(qb.y + k0.y), a10);
            a00 = fmaf(wvv.z, sig2(qa.z + k0.z), a00);
            a10 = fmaf(wvv.z, sig2(qb.z + k0.z), a10);
            a00 = fmaf(wvv.w, sig2(qa.w + k0.w), a00);
            a10 = fmaf(wvv.w, sig2(qb.w + k0.w), a10);
        }
    }

    // ---- mask + softmax ----
    int kv0 = w*64 + lane, kv1 = kv0 + 512;
    bool m0v = (kv0 < vl), m1v = (kv1 < vl);
    float s00 = m0v ? -2.f*a00 : -1e6f;
    float s10 = m0v ? -2.f*a10 : -1e6f;
    float s01 = m1v ? -2.f*a01 : -1e6f;
    float s11 = m1v ? -2.f*a11 : -1e6f;

    float m0 = fmaxf(s00, s01), m1 = fmaxf(s10, s11);
#pragma unroll
    for (int off = 32; off; off >>= 1) {
        m0 = fmaxf(m0, __shfl_xor(m0, off));
        m1 = fmaxf(m1, __shfl_xor(m1, off));
    }
    if (lane == 0) red_m[w] = make_float2(m0, m1);
    __syncthreads();
    {
        float2 mm = red_m[0];
#pragma unroll
        for (int ww = 1; ww < 8; ++ww) {
            float2 t = red_m[ww];
            mm.x = fmaxf(mm.x, t.x); mm.y = fmaxf(mm.y, t.y);
        }
        m0 = mm.x; m1 = mm.y;
    }

    float e00 = __builtin_amdgcn_exp2f((s00 - m0) * LOG2E);
    float e10 = __builtin_amdgcn_exp2f((s10 - m1) * LOG2E);
    float e01 = __builtin_amdgcn_exp2f((s01 - m0) * LOG2E);
    float e11 = __builtin_amdgcn_exp2f((s11 - m1) * LOG2E);
    e2_s[kv0] = make_float2(e00, e10);
    e2_s[kv1] = make_float2(e01, e11);
    float l0 = e00 + e01, l1 = e10 + e11;
#pragma unroll
    for (int off = 32; off; off >>= 1) {
        l0 += __shfl_xor(l0, off);
        l1 += __shfl_xor(l1, off);
    }
    if (lane == 0) red_s[w] = make_float2(l0, l1);
    __syncthreads();

    // ---- PV: wave w takes kv = w, w+8, ... (< vl; e==0 beyond) ----
    int kv_end = (vl == 0) ? 1024 : vl;
    float4 ac0 = {0,0,0,0}, ac1 = {0,0,0,0};
    const float4* V4 = (const float4*)values + (size_t)b*65536 + lane;
#pragma unroll 2
    for (int k2 = w; k2 < kv_end; k2 += 8) {
        float4 vv = V4[(size_t)k2*64];      // coalesced 1 KB/wave
        float2 ee = e2_s[k2];               // broadcast
        ac0.x = fmaf(ee.x, vv.x, ac0.x); ac0.y = fmaf(ee.x, vv.y, ac0.y);
        ac0.z = fmaf(ee.x, vv.z, ac0.z); ac0.w = fmaf(ee.x, vv.w, ac0.w);
        ac1.x = fmaf(ee.y, vv.x, ac1.x); ac1.y = fmaf(ee.y, vv.y, ac1.y);
        ac1.z = fmaf(ee.y, vv.z, ac1.z); ac1.w = fmaf(ee.y, vv.w, ac1.w);
    }
    po[w][0][lane] = ac0;
    po[w][1][lane] = ac1;
    __syncthreads();

    // ---- combine 8 wave partials: thread -> one output element ----
    int qq  = tid >> 8;                 // 0..1
    int col = tid & 255;
    float ssum = 0.f;
#pragma unroll
    for (int ww = 0; ww < 8; ++ww) {
        float2 t = red_s[ww];
        ssum += qq ? t.y : t.x;
    }
    const float* pp = (const float*)po;     // [(w*2+q)*256 + col]
    float r = 0.f;
#pragma unroll
    for (int ww = 0; ww < 8; ++ww) r += pp[(ww*2 + qq)*256 + col];
    out[((size_t)(b*256 + q0 + qq))*256 + col] = r / ssum;
}

extern "C" void kernel_launch(void* const* d_in, const int* in_sizes, int n_in,
                              void* d_out, int out_size, void* d_ws, size_t ws_size,
                              hipStream_t stream)
{
    const float* queries = (const float*)d_in[0];   // [4,256,128]
    const float* keys    = (const float*)d_in[1];   // [4,1024,128]
    const float* values  = (const float*)d_in[2];   // [4,1024,256]
    const int*   vlens   = (const int*)d_in[3];     // [4]
    const float* Wq      = (const float*)d_in[4];   // [128,128]
    const float* Wk      = (const float*)d_in[5];   // [128,128]
    const float* wv      = (const float*)d_in[6];   // [128]
    float* out = (float*)d_out;                     // [4,256,256]

    float* qc  = (float*)d_ws;                      // 4*256*128 floats
    float* kct = qc + 4*256*128;                    // 4*16*32*64*4 floats

    proj_kernel<<<640, 256, 0, stream>>>(queries, keys, Wq, Wk, vlens, qc, kct);
    attn_kernel<<<dim3(128, 4), 512, 0, stream>>>(qc, kct, values, vlens, wv, out);
}